// Round 3
// baseline (7912.296 us; speedup 1.0000x reference)
//
#include <hip/hip_runtime.h>
#include <hip/hip_bf16.h>

// Max-tree (component tree) per channel, 64x64x3.
// Outputs (float32): parents [3,4096] then altitudes [3,4096].
//
// Parallel strategy (Wilkinson-style merge of sub-max-trees):
//  - ranks = stable descending sort position (distinct!) act as altitudes;
//    the union phase of the reference is purely order-driven, so the
//    rank-image max-tree's uncompressed pixel-parent == reference's.
//  - 16 row-strips per channel built serially in parallel (16 waves/block)
//  - 4 levels of boundary merges via connect() (merge two sorted root paths)
//  - canon closed form g[p] = climb-from-parent-while-f-equal (validated r2)

#define N_PIX 4096
#define CH 3

// ---------------------------------------------------------------------------
// Kernel 1: stable descending rank: rank(p) = #{f[q]>f[p]} + #{f[q]==f[p],q<p}
// ---------------------------------------------------------------------------
__global__ __launch_bounds__(256) void ct_rank(const float* __restrict__ vw,
                                               int* __restrict__ rank_g) {
    __shared__ __align__(16) float vals[N_PIX];
    const int c   = blockIdx.x >> 4;
    const int seg = blockIdx.x & 15;
    const int tid = threadIdx.x;
    for (int i = tid; i < N_PIX; i += 256) vals[i] = vw[i * CH + c];
    __syncthreads();

    const int   p  = (seg << 8) + tid;
    const float vp = vals[p];
    int cnt = 0;
    const float4* v4 = reinterpret_cast<const float4*>(vals);
#pragma unroll 4
    for (int j4 = 0; j4 < N_PIX / 4; ++j4) {
        float4 q = v4[j4];
        int j = j4 << 2;
        cnt += (q.x > vp) || ((q.x == vp) && (j     < p));
        cnt += (q.y > vp) || ((q.y == vp) && (j + 1 < p));
        cnt += (q.z > vp) || ((q.z == vp) && (j + 2 < p));
        cnt += (q.w > vp) || ((q.w == vp) && (j + 3 < p));
    }
    rank_g[(c << 12) + p] = cnt;
}

// ---------------------------------------------------------------------------
// Kernel 2: per-channel block: strip builds + hierarchical boundary merges
// + canon + output. word[p] = (rank<<12) | parent  (both < 4096).
// ---------------------------------------------------------------------------
__global__ __launch_bounds__(1024) void ct_main(const float* __restrict__ vw,
                                                const int* __restrict__ rank_g,
                                                float* __restrict__ out) {
    __shared__ unsigned       word[N_PIX];      // 16 KB
    __shared__ unsigned short rank16[N_PIX];    // 8 KB
    __shared__ unsigned short parent16[N_PIX];  // 8 KB
    __shared__ short          zpar[N_PIX];      // 8 KB (-1 = unprocessed)
    __shared__ unsigned short sorder[N_PIX];    // 8 KB (per-strip order)

    const int c    = blockIdx.x;
    const int tid  = threadIdx.x;
    const int wv   = tid >> 6;
    const int lane = tid & 63;

    // ---- phase 1: init -----------------------------------------------------
    for (int p = tid; p < N_PIX; p += 1024) {
        rank16[p]   = (unsigned short)rank_g[(c << 12) + p];
        parent16[p] = (unsigned short)p;
        zpar[p]     = -1;
    }
    __syncthreads();

    // ---- phase 2: per-strip order (rank-sorted, ranks globally distinct) ---
    {
        const int base = wv << 8;   // strip wv = pixels [256wv, 256wv+256)
        int myp[4]; unsigned myr[4]; int cnt[4] = {0, 0, 0, 0};
#pragma unroll
        for (int k = 0; k < 4; ++k) {
            myp[k] = base + (k << 6) + lane;
            myr[k] = rank16[myp[k]];
        }
        for (int q = 0; q < 256; ++q) {
            unsigned rq = rank16[base + q];   // broadcast read
            cnt[0] += rq < myr[0]; cnt[1] += rq < myr[1];
            cnt[2] += rq < myr[2]; cnt[3] += rq < myr[3];
        }
#pragma unroll
        for (int k = 0; k < 4; ++k) sorder[base + cnt[k]] = (unsigned short)myp[k];
    }
    __syncthreads();

    // ---- phase 3: serial Berger per strip (lane 0 of each wave) ------------
    // Batched pre-state finds: all reads before all writes within an
    // iteration is equivalent to the sequential inner loop (all unions
    // write the same value p; pre-state roots are the true roots).
    if (lane == 0) {
        const int base  = wv << 8;
        const int rowlo = wv << 2, rowhi = rowlo + 3;
        for (int i = 0; i < 256; ++i) {
            const int p   = sorder[base + i];
            const int row = p >> 6, col = p & 63;
            zpar[p] = (short)p;   // mark processed (parent16[p] == p from init)

            const bool va[4] = { row > rowlo, row < rowhi, col > 0, col < 63 };
            const int  nn[4] = { p - 64, p + 64, p - 1, p + 1 };
            int z[4], cz[4], r[4];
#pragma unroll
            for (int k = 0; k < 4; ++k) {       // batch 1: neighbor zpar
                int a = nn[k]; a = a < 0 ? 0 : (a > N_PIX - 1 ? N_PIX - 1 : a);
                z[k] = zpar[a];
            }
#pragma unroll
            for (int k = 0; k < 4; ++k) r[k] = (va[k] && z[k] >= 0) ? z[k] : -1;
#pragma unroll
            for (int k = 0; k < 4; ++k) {       // batch 2: root confirm
                int a = r[k] < 0 ? 0 : r[k];
                cz[k] = zpar[a];
            }
#pragma unroll
            for (int k = 0; k < 4; ++k) {       // finish walks (pre-state)
                if (r[k] >= 0) {
                    int rr = r[k], rc = cz[k];
                    while (rc != rr) { rr = rc; rc = zpar[rr]; }
                    r[k] = rr;
                }
            }
#pragma unroll
            for (int k = 0; k < 4; ++k) {       // unions + compression
                if (r[k] >= 0) {
                    if (r[k] != p) { parent16[r[k]] = (unsigned short)p;
                                     zpar[r[k]]     = (short)p; }
                    zpar[nn[k]] = (short)p;
                }
            }
        }
    }
    __syncthreads();

    // ---- phase 3.5: pack word = (rank<<12) | parent ------------------------
    for (int p = tid; p < N_PIX; p += 1024)
        word[p] = ((unsigned)rank16[p] << 12) | (unsigned)parent16[p];
    __syncthreads();

    // ---- phase 4: hierarchical boundary merges (Wilkinson connect) ---------
    // Level L: 8>>L parallel merges; regions disjoint; smaller rank = higher f.
    for (int L = 0; L < 4; ++L) {
        const int nM = 8 >> L;
        if (wv < nM && lane == 0) {
            const int rtop = ((((wv << 1) | 1) << L) << 2) - 1;  // 4*(2w+1)*2^L - 1
            const int xb = rtop << 6;
            for (int col = 0; col < 64; ++col) {
                int x = xb + col, y = x + 64;
                unsigned wx = word[x], wy = word[y];
                if ((wx >> 12) > (wy >> 12)) {
                    int t = x; x = y; y = t;
                    unsigned tw = wx; wx = wy; wy = tw;
                }
                while (x != y) {                 // invariant: rank x < rank y
                    const int z = wx & 0xFFF;    // parent[x]
                    if (z != x) {
                        const unsigned wz = word[z];
                        if ((wz >> 12) <= (wy >> 12)) {        // f(z) >= f(y): climb
                            x = z; wx = wz;
                        } else {                                // splice y above z
                            word[x] = (wx & 0xFFFFF000u) | (unsigned)y;
                            x = y; wx = wy; y = z; wy = wz;
                        }
                    } else {                                    // x is root: attach
                        word[x] = (wx & 0xFFFFF000u) | (unsigned)y;
                        break;
                    }
                }
            }
        }
        __syncthreads();
    }

    // ---- phase 5: canon (g[p] = climb-from-parent-while-f-equal) + output --
    for (int p = tid; p < N_PIX; p += 1024) {
        int q = word[p] & 0xFFF;
        float fq = vw[q * CH + c];
        for (;;) {
            int qp = word[q] & 0xFFF;
            if (qp == q) break;                  // root
            if (vw[qp * CH + c] != fq) break;    // altitude changes
            q = qp;
        }
        out[(c << 12) + p] = (float)q;
        out[CH * N_PIX + (c << 12) + p] = vw[p * CH + c];
    }
}

extern "C" void kernel_launch(void* const* d_in, const int* in_sizes, int n_in,
                              void* d_out, int out_size, void* d_ws, size_t ws_size,
                              hipStream_t stream) {
    const float* vw = (const float*)d_in[0];
    float* out = (float*)d_out;

    int* rank_g = (int*)d_ws;   // 3*4096 ints

    ct_rank<<<48, 256, 0, stream>>>(vw, rank_g);
    ct_main<<<CH, 1024, 0, stream>>>(vw, rank_g, out);
}

// Round 4
// 2294.782 us; speedup vs baseline: 3.4480x; 3.4480x over previous
//
#include <hip/hip_runtime.h>
#include <hip/hip_bf16.h>

// Max-tree (component tree) per channel, 64x64x3. Outputs (float32):
// parents [3,4096] then altitudes [3,4096].
//
// ranks = stable descending sort position (distinct) act as altitudes; the
// rank-image max-tree's uncompressed pixel-parent == reference's (union phase
// is purely order-driven). Strategy: 16 per-strip Berger builds in parallel,
// then hierarchical boundary merges (Wilkinson connect) accelerated by a
// skip-pointer array with path-halving, then closed-form canonicalization.

#define N_PIX 4096
#define CH 3

// ---------------------------------------------------------------------------
// K1: stable descending rank: rank(p) = #{f[q]>f[p]} + #{f[q]==f[p], q<p}
// ---------------------------------------------------------------------------
__global__ __launch_bounds__(256) void ct_rank(const float* __restrict__ vw,
                                               int* __restrict__ rank_g) {
    __shared__ __align__(16) float vals[N_PIX];
    const int c   = blockIdx.x >> 4;
    const int seg = blockIdx.x & 15;
    const int tid = threadIdx.x;
    for (int i = tid; i < N_PIX; i += 256) vals[i] = vw[i * CH + c];
    __syncthreads();

    const int   p  = (seg << 8) + tid;
    const float vp = vals[p];
    int cnt = 0;
    const float4* v4 = reinterpret_cast<const float4*>(vals);
#pragma unroll 4
    for (int j4 = 0; j4 < N_PIX / 4; ++j4) {
        float4 q = v4[j4];
        int j = j4 << 2;
        cnt += (q.x > vp) || ((q.x == vp) && (j     < p));
        cnt += (q.y > vp) || ((q.y == vp) && (j + 1 < p));
        cnt += (q.z > vp) || ((q.z == vp) && (j + 2 < p));
        cnt += (q.w > vp) || ((q.w == vp) && (j + 3 < p));
    }
    rank_g[(c << 12) + p] = cnt;
}

// ---------------------------------------------------------------------------
// K2: per-strip serial Berger build. 48 blocks = (c, strip), 1 wave each.
// Local pixel index l in [0,256); strip covers rows [4s, 4s+3].
// word_g[p] = (rank(p)<<12) | parent(p)  (both < 4096).
// ---------------------------------------------------------------------------
__global__ __launch_bounds__(64) void ct_build(const int* __restrict__ rank_g,
                                               unsigned* __restrict__ word_g) {
    __shared__ unsigned short rankS[256];
    __shared__ unsigned short orderS[256];
    __shared__ unsigned short parS[256];
    __shared__ short          zparS[256];
    const int c     = blockIdx.x >> 4;
    const int strip = blockIdx.x & 15;
    const int lane  = threadIdx.x;
    const int base  = strip << 8;

#pragma unroll
    for (int k = 0; k < 4; ++k) {
        const int l = (k << 6) + lane;
        rankS[l] = (unsigned short)rank_g[(c << 12) + base + l];
        parS[l]  = (unsigned short)l;
        zparS[l] = -1;
    }
    __syncthreads();

    // strip-local processing order (ranks globally distinct -> strict <)
    {
        int cnt[4] = {0, 0, 0, 0};
        unsigned myr[4];
#pragma unroll
        for (int k = 0; k < 4; ++k) myr[k] = rankS[(k << 6) + lane];
        for (int q = 0; q < 256; ++q) {
            const unsigned rq = rankS[q];   // broadcast
            cnt[0] += rq < myr[0]; cnt[1] += rq < myr[1];
            cnt[2] += rq < myr[2]; cnt[3] += rq < myr[3];
        }
#pragma unroll
        for (int k = 0; k < 4; ++k) orderS[cnt[k]] = (unsigned short)((k << 6) + lane);
    }
    __syncthreads();

    // serial Berger with batched pre-state finds (validated in r3)
    if (lane == 0) {
        for (int i = 0; i < 256; ++i) {
            const int l    = orderS[i];
            const int lrow = l >> 6, col = l & 63;
            zparS[l] = (short)l;

            const bool va[4] = { lrow > 0, lrow < 3, col > 0, col < 63 };
            const int  nn[4] = { l - 64, l + 64, l - 1, l + 1 };
            int z[4], cz[4], r[4];
#pragma unroll
            for (int k = 0; k < 4; ++k) z[k] = zparS[nn[k] & 255];
#pragma unroll
            for (int k = 0; k < 4; ++k) r[k] = (va[k] && z[k] >= 0) ? z[k] : -1;
#pragma unroll
            for (int k = 0; k < 4; ++k) cz[k] = zparS[r[k] < 0 ? 0 : r[k]];
#pragma unroll
            for (int k = 0; k < 4; ++k) {
                if (r[k] >= 0) {
                    int rr = r[k], rc = cz[k];
                    while (rc != rr) { rr = rc; rc = zparS[rr]; }
                    r[k] = rr;
                }
            }
#pragma unroll
            for (int k = 0; k < 4; ++k) {
                if (r[k] >= 0) {
                    if (r[k] != l) { parS[r[k]]  = (unsigned short)l;
                                     zparS[r[k]] = (short)l; }
                    zparS[nn[k]] = (short)l;
                }
            }
        }
    }
    __syncthreads();
#pragma unroll
    for (int k = 0; k < 4; ++k) {
        const int l = (k << 6) + lane;
        word_g[(c << 12) + base + l] =
            ((unsigned)rankS[l] << 12) | (unsigned)(base + parS[l]);
    }
}

// ---------------------------------------------------------------------------
// K3: hierarchical boundary merges with skip-compressed connect + canon.
// skipw[x] = (rank(t)<<12)|t where t is an ancestor of x (or x itself) in the
// current forest. Splices only INSERT nodes into root paths, so ancestorship
// persists across connects and levels; ranks ascend along root paths, so a
// jump to t is safe whenever rank(t) <= rank(y). Path-halving on jumps.
// ---------------------------------------------------------------------------
__global__ __launch_bounds__(512) void ct_merge(const float* __restrict__ vw,
                                                const unsigned* __restrict__ word_g,
                                                float* __restrict__ out) {
    __shared__ unsigned word[N_PIX];    // 16 KB
    __shared__ unsigned skipw[N_PIX];   // 16 KB
    const int c    = blockIdx.x;
    const int tid  = threadIdx.x;
    const int wv   = tid >> 6;
    const int lane = tid & 63;

    for (int p = tid; p < N_PIX; p += 512) {
        const unsigned w = word_g[(c << 12) + p];
        word[p]  = w;
        skipw[p] = (w & 0xFFFFF000u) | (unsigned)p;   // self target
    }
    __syncthreads();

    for (int L = 0; L < 4; ++L) {
        const int nM = 8 >> L;
        if (wv < nM && lane == 0) {
            const int rtop = ((((wv << 1) | 1) << L) << 2) - 1;
            const int xb = rtop << 6;
            for (int col = 0; col < 64; ++col) {
                int x = xb + col, y = x + 64;
                unsigned wx = word[x], wy = word[y];
                if ((wx >> 12) > (wy >> 12)) {
                    int t = x; x = y; y = t;
                    unsigned tw = wx; wx = wy; wy = tw;
                }
                while (x != y) {                  // invariant: rank x < rank y
                    const unsigned ry = wy >> 12;
                    // ---- skip fast-forward with path-halving ----
                    unsigned sk = skipw[x];
                    for (;;) {
                        const int s = sk & 0xFFF;
                        if (s == x || (sk >> 12) > ry) break;
                        const unsigned sk2 = skipw[s];
                        if ((sk2 >> 12) <= ry) skipw[x] = sk2;
                        x = s; sk = sk2;
                        if (x == y) break;
                    }
                    if (x == y) break;
                    wx = word[x];
                    // ---- plain step ----
                    const int z = wx & 0xFFF;
                    if (z != x) {
                        const unsigned wz = word[z];
                        if ((wz >> 12) <= ry) {            // climb; memo ancestor
                            skipw[x] = (wz & 0xFFFFF000u) | (unsigned)z;
                            x = z; wx = wz;
                        } else {                            // splice y above z
                            word[x] = (wx & 0xFFFFF000u) | (unsigned)y;
                            x = y; wx = wy; y = z; wy = wz;
                        }
                    } else {                                // x is root: attach
                        word[x] = (wx & 0xFFFFF000u) | (unsigned)y;
                        break;
                    }
                }
            }
        }
        __syncthreads();
    }

    // canon (g[p] = climb-from-parent-while-f-equal, validated r2/r3) + output
    for (int p = tid; p < N_PIX; p += 512) {
        int q = word[p] & 0xFFF;
        const float fq = vw[q * CH + c];
        for (;;) {
            const int qp = word[q] & 0xFFF;
            if (qp == q) break;
            if (vw[qp * CH + c] != fq) break;
            q = qp;
        }
        out[(c << 12) + p] = (float)q;
        out[CH * N_PIX + (c << 12) + p] = vw[p * CH + c];
    }
}

extern "C" void kernel_launch(void* const* d_in, const int* in_sizes, int n_in,
                              void* d_out, int out_size, void* d_ws, size_t ws_size,
                              hipStream_t stream) {
    const float* vw = (const float*)d_in[0];
    float* out = (float*)d_out;

    int*      rank_g = (int*)d_ws;                       // 3*4096 ints
    unsigned* word_g = (unsigned*)(rank_g + CH * N_PIX); // 3*4096 uints

    ct_rank <<<48, 256, 0, stream>>>(vw, rank_g);
    ct_build<<<48, 64, 0, stream>>>(rank_g, word_g);
    ct_merge<<<CH, 512, 0, stream>>>(vw, word_g, out);
}

// Round 5
// 590.771 us; speedup vs baseline: 13.3932x; 3.8844x over previous
//
#include <hip/hip_runtime.h>
#include <hip/hip_bf16.h>

// Max-tree (component tree) per channel, 64x64x3. Outputs (float32):
// parents [3,4096] then altitudes [3,4096].
//
// ranks = stable descending sort position (distinct, 0 = highest f) act as
// altitudes; the rank-image max-tree's uncompressed pixel-parent equals the
// reference's (union phase is purely order-driven; validated rounds 2-4).
// With distinct ranks the tree is UNIQUE (parent[x] = min-rank q > rank(x)
// connected to x at level rank(q)) => order-independent => we can build it
// with a fully concurrent CAS-based ordered union over all 8064 4-adjacency
// edges (GPU max-tree construction a la Blin et al.), then canonicalize with
// the closed form g[p] = climb-from-parent-while-f-equal (validated r2-r4).
//
// parw[x] = (rank(parent(x))<<12) | parent(x); root: (rank(x)<<12)|x.
// One LDS read per walk step; CAS full-word. ABA-safe: non-root parent-rank
// strictly decreases (splices insert lower-rank nodes only); root->attached
// is a one-time transition.

#define N_PIX 4096
#define CH 3

// ---------------------------------------------------------------------------
// K1: stable descending rank: rank(p) = #{f[q]>f[p]} + #{f[q]==f[p], q<p}
// ---------------------------------------------------------------------------
__global__ __launch_bounds__(256) void ct_rank(const float* __restrict__ vw,
                                               int* __restrict__ rank_g) {
    __shared__ __align__(16) float vals[N_PIX];
    const int c   = blockIdx.x >> 4;
    const int seg = blockIdx.x & 15;
    const int tid = threadIdx.x;
    for (int i = tid; i < N_PIX; i += 256) vals[i] = vw[i * CH + c];
    __syncthreads();

    const int   p  = (seg << 8) + tid;
    const float vp = vals[p];
    int cnt = 0;
    const float4* v4 = reinterpret_cast<const float4*>(vals);
#pragma unroll 4
    for (int j4 = 0; j4 < N_PIX / 4; ++j4) {
        float4 q = v4[j4];
        int j = j4 << 2;
        cnt += (q.x > vp) || ((q.x == vp) && (j     < p));
        cnt += (q.y > vp) || ((q.y == vp) && (j + 1 < p));
        cnt += (q.z > vp) || ((q.z == vp) && (j + 2 < p));
        cnt += (q.w > vp) || ((q.w == vp) && (j + 3 < p));
    }
    rank_g[(c << 12) + p] = cnt;
}

// ---------------------------------------------------------------------------
// K2: concurrent ordered union over all edges + canon + output.
// One block per channel, 1024 threads.
// ---------------------------------------------------------------------------
__global__ __launch_bounds__(1024) void ct_tree(const float* __restrict__ vw,
                                                const int* __restrict__ rank_g,
                                                float* __restrict__ out) {
    __shared__ unsigned       parw[N_PIX];     // 16 KB
    __shared__ unsigned short rank16[N_PIX];   // 8 KB
    const int c   = blockIdx.x;
    const int tid = threadIdx.x;

    for (int p = tid; p < N_PIX; p += 1024) {
        const unsigned r = (unsigned)rank_g[(c << 12) + p];
        rank16[p] = (unsigned short)r;
        parw[p]   = (r << 12) | (unsigned)p;
    }
    __syncthreads();

    // 8064 edges: horizontal id = row*63+col (col<63), vertical after.
    for (int e = tid; e < 8064; e += 1024) {
        int x, y;
        if (e < 4032) { const int row = e / 63; x = row * 64 + (e - row * 63); y = x + 1; }
        else          { const int e2 = e - 4032; x = ((e2 >> 6) << 6) + (e2 & 63); y = x + 64; }
        unsigned rx = rank16[x], ry = rank16[y];
        if (rx > ry) { int t = x; x = y; y = t; unsigned tr = rx; rx = ry; ry = tr; }

        // invariant: rank(x)=rx < ry=rank(y); insert y into x's root path.
        for (;;) {
            const unsigned w  = *((volatile unsigned*)&parw[x]);
            const unsigned p  = w & 0xFFFu;
            const unsigned rp = w >> 12;
            if (p == (unsigned)x) {                       // x is root: attach y
                if (atomicCAS(&parw[x], w, (ry << 12) | (unsigned)y) == w) break;
            } else if (rp < ry) {                         // climb
                x = (int)p; rx = rp;
            } else if (rp > ry) {                         // splice y between x,p
                if (atomicCAS(&parw[x], w, (ry << 12) | (unsigned)y) == w) {
                    x = y; rx = ry; y = (int)p; ry = rp;  // continue inserting p
                }
            } else break;                                 // rp == ry => p == y
        }
    }
    __syncthreads();

    // canon (g[p] = climb-from-parent-while-f-equal, validated r2-r4) + output
    for (int p = tid; p < N_PIX; p += 1024) {
        int q = parw[p] & 0xFFF;
        const float fq = vw[q * CH + c];
        for (;;) {
            const int qp = parw[q] & 0xFFF;
            if (qp == q) break;
            if (vw[qp * CH + c] != fq) break;
            q = qp;
        }
        out[(c << 12) + p] = (float)q;
        out[CH * N_PIX + (c << 12) + p] = vw[p * CH + c];
    }
}

extern "C" void kernel_launch(void* const* d_in, const int* in_sizes, int n_in,
                              void* d_out, int out_size, void* d_ws, size_t ws_size,
                              hipStream_t stream) {
    const float* vw = (const float*)d_in[0];
    float* out = (float*)d_out;

    int* rank_g = (int*)d_ws;   // 3*4096 ints

    ct_rank<<<48, 256, 0, stream>>>(vw, rank_g);
    ct_tree<<<CH, 1024, 0, stream>>>(vw, rank_g, out);
}

// Round 6
// 496.544 us; speedup vs baseline: 15.9347x; 1.1898x over previous
//
#include <hip/hip_runtime.h>
#include <hip/hip_bf16.h>

// Max-tree (component tree) per channel, 64x64x3. Outputs (float32):
// parents [3,4096] then altitudes [3,4096].
//
// ranks = stable descending sort position (distinct, 0 = highest f) act as
// altitudes; the rank-image max-tree's uncompressed pixel-parent equals the
// reference's (union phase is purely order-driven; validated rounds 2-5).
// With distinct ranks the tree is UNIQUE => order-independent => concurrent
// CAS-based ordered union over all 8064 edges (validated r5), accelerated by
// skip-pointer hints with path-halving (validated serially in r4):
//   skipw[x] = (rank(t)<<12)|t, t an ancestor of x (or x). Splices only
//   INSERT nodes into root paths => ancestorship persists forever; ranks
//   ascend along root paths => jump safe whenever rank(t) <= ry (distinct
//   ranks: rank(t)==ry <=> t==y). Plain 32-bit LDS stores are word-atomic;
//   any racy hint is still a valid ancestor.
// parw[x] = (rank(parent(x))<<12)|parent(x); root: (rank(x)<<12)|x. CAS is
// ABA-safe: non-root parent-rank strictly decreases; root->attached once.
// Canon closed form g[p] = climb-from-parent-while-f-equal (validated r2-r5).

#define N_PIX 4096
#define CH 3

// ---------------------------------------------------------------------------
// K1: stable descending rank: rank(p) = #{f[q]>f[p]} + #{f[q]==f[p], q<p}
// ---------------------------------------------------------------------------
__global__ __launch_bounds__(256) void ct_rank(const float* __restrict__ vw,
                                               int* __restrict__ rank_g) {
    __shared__ __align__(16) float vals[N_PIX];
    const int c   = blockIdx.x >> 4;
    const int seg = blockIdx.x & 15;
    const int tid = threadIdx.x;
    for (int i = tid; i < N_PIX; i += 256) vals[i] = vw[i * CH + c];
    __syncthreads();

    const int   p  = (seg << 8) + tid;
    const float vp = vals[p];
    int cnt = 0;
    const float4* v4 = reinterpret_cast<const float4*>(vals);
#pragma unroll 4
    for (int j4 = 0; j4 < N_PIX / 4; ++j4) {
        float4 q = v4[j4];
        int j = j4 << 2;
        cnt += (q.x > vp) || ((q.x == vp) && (j     < p));
        cnt += (q.y > vp) || ((q.y == vp) && (j + 1 < p));
        cnt += (q.z > vp) || ((q.z == vp) && (j + 2 < p));
        cnt += (q.w > vp) || ((q.w == vp) && (j + 3 < p));
    }
    rank_g[(c << 12) + p] = cnt;
}

// ---------------------------------------------------------------------------
// K2: concurrent ordered union over all edges (skip-accelerated) + canon.
// One block per channel, 1024 threads.
// ---------------------------------------------------------------------------
__global__ __launch_bounds__(1024) void ct_tree(const float* __restrict__ vw,
                                                const int* __restrict__ rank_g,
                                                float* __restrict__ out) {
    __shared__ unsigned       parw[N_PIX];     // 16 KB
    __shared__ unsigned       skipw[N_PIX];    // 16 KB
    __shared__ unsigned short rank16[N_PIX];   // 8 KB
    const int c   = blockIdx.x;
    const int tid = threadIdx.x;

    for (int p = tid; p < N_PIX; p += 1024) {
        const unsigned r = (unsigned)rank_g[(c << 12) + p];
        rank16[p] = (unsigned short)r;
        parw[p]   = (r << 12) | (unsigned)p;
        skipw[p]  = (r << 12) | (unsigned)p;   // self (no ancestor known yet)
    }
    __syncthreads();

    volatile unsigned* vpar = parw;
    volatile unsigned* vskp = skipw;

    // 8064 edges: horizontal id = row*63+col (col<63), vertical after.
    for (int e = tid; e < 8064; e += 1024) {
        int x, y;
        if (e < 4032) { const int row = e / 63; x = row * 64 + (e - row * 63); y = x + 1; }
        else          { const int e2 = e - 4032; x = ((e2 >> 6) << 6) + (e2 & 63); y = x + 64; }
        unsigned rx = rank16[x], ry = rank16[y];
        if (rx > ry) { int t = x; x = y; y = t; unsigned tr = rx; rx = ry; ry = tr; }

        // invariant: rank(x) < ry = rank(y); insert y into x's root path.
        for (;;) {
            // ---- skip fast-forward with path-halving ----
            unsigned sk = vskp[x];
            for (;;) {
                const unsigned s = sk & 0xFFFu;
                if (s == (unsigned)x || (sk >> 12) > ry) break;
                const unsigned sk2 = vskp[s];
                if ((sk2 >> 12) <= ry && (sk2 & 0xFFFu) != s) skipw[x] = sk2;
                x = (int)s; sk = sk2;
            }
            if ((unsigned)x == (unsigned)y) break;   // reached y: already linked

            // ---- plain step ----
            const unsigned w  = vpar[x];
            const unsigned p  = w & 0xFFFu;
            const unsigned rp = w >> 12;
            if (p == (unsigned)x) {                       // x is root: attach y
                if (atomicCAS(&parw[x], w, (ry << 12) | (unsigned)y) == w) {
                    skipw[x] = (ry << 12) | (unsigned)y;
                    break;
                }
            } else if (rp < ry) {                         // climb (memo parent)
                skipw[x] = w;
                x = (int)p;
            } else if (rp > ry) {                         // splice y between x,p
                if (atomicCAS(&parw[x], w, (ry << 12) | (unsigned)y) == w) {
                    skipw[x] = (ry << 12) | (unsigned)y;
                    x = y; y = (int)p; ry = rp;           // continue inserting p
                }
            } else break;                                 // rp == ry => p == y
        }
    }
    __syncthreads();

    // canon (g[p] = climb-from-parent-while-f-equal, validated r2-r5) + output
    for (int p = tid; p < N_PIX; p += 1024) {
        int q = parw[p] & 0xFFF;
        const float fq = vw[q * CH + c];
        for (;;) {
            const int qp = parw[q] & 0xFFF;
            if (qp == q) break;
            if (vw[qp * CH + c] != fq) break;
            q = qp;
        }
        out[(c << 12) + p] = (float)q;
        out[CH * N_PIX + (c << 12) + p] = vw[p * CH + c];
    }
}

extern "C" void kernel_launch(void* const* d_in, const int* in_sizes, int n_in,
                              void* d_out, int out_size, void* d_ws, size_t ws_size,
                              hipStream_t stream) {
    const float* vw = (const float*)d_in[0];
    float* out = (float*)d_out;

    int* rank_g = (int*)d_ws;   // 3*4096 ints

    ct_rank<<<48, 256, 0, stream>>>(vw, rank_g);
    ct_tree<<<CH, 1024, 0, stream>>>(vw, rank_g, out);
}